// Round 1
// 5087.736 us; speedup vs baseline: 1.3527x; 1.3527x over previous
//
#include <hip/hip_runtime.h>
#include <math.h>

#define BB 128
#define TT 512
#define FF 128
#define HH 512
#define NR 2048      // gate rows, row = 4*j + g
#define HB (HH*BB)   // 65536 words per h state

typedef __attribute__((ext_vector_type(8))) short short8;   // 8 bf16 (A/B frag)
typedef __attribute__((ext_vector_type(4))) float f32x4;    // MFMA C/D frag
typedef unsigned int uint;
typedef unsigned short ushort;

#define MFMA __builtin_amdgcn_mfma_f32_16x16x32_bf16

__device__ __forceinline__ ushort f2bf(float f) {           // fp32 -> bf16 RNE
  uint u = __float_as_uint(f);
  u += 0x7fff + ((u >> 16) & 1);
  return (ushort)(u >> 16);
}

// ---------------- prep kernels ----------------

__global__ __launch_bounds__(256) void k_zero(float* __restrict__ p, int n) {
  int i = blockIdx.x * 256 + threadIdx.x;
  if (i < n) p[i] = 0.f;
}

// bias [2048] (col = g*512 + j) -> bp[j*4+g]
__global__ __launch_bounds__(256) void k_rearr_b(const float* __restrict__ src,
                                                 float* __restrict__ dst) {
  int idx = blockIdx.x * 256 + threadIdx.x;   // 2048
  int j = idx & 511, g = idx >> 9;
  dst[j * 4 + g] = src[idx];
}

// [K][2048] matrix -> A-fragment order, bf16 hi/lo split. K = 32<<ktsh... KT=1<<ktsh k-tiles.
// dst[((jb*KT + kt)*64 + L)*16 + term*8 + j8]:
//   k = kt*32 + (L>>4)*8 + j8 ; m = L&15 ; j = jb*4 + (m>>2) ; g = m&3
__global__ __launch_bounds__(256) void k_pack_A(const float* __restrict__ src,
                                                ushort* __restrict__ dst, int ktsh) {
  int idx = blockIdx.x * 256 + threadIdx.x;   // over 128 * KT * 64 * 8
  int KTm1 = (1 << ktsh) - 1;
  int j8 = idx & 7;
  int L = (idx >> 3) & 63;
  int kt = (idx >> 9) & KTm1;
  int jb = idx >> (9 + ktsh);
  int k = kt * 32 + (L >> 4) * 8 + j8;
  int m = L & 15;
  int j = jb * 4 + (m >> 2);
  int g = m & 3;
  float v = src[(size_t)k * NR + g * HH + j];
  ushort hi = f2bf(v);
  float fhi = __uint_as_float(((uint)hi) << 16);
  ushort lo = f2bf(v - fhi);
  size_t base = ((size_t)((jb << ktsh) + kt) * 64 + L) * 16;
  dst[base + j8] = hi;
  dst[base + 8 + j8] = lo;
}

// ---------------- fused persistent 2-layer LSTM ----------------
// 256 blocks x 256 thr, 1 block/CU (proven co-resident). Block bx = jb*2+bh:
// jb owns 4 hidden units (16 gate rows), bh the batch half; 4 waves = 4 col
// tiles. Flag protocol identical to the proven k_rec: agent-scope relaxed
// atomic h stores (write-through, drained by __syncthreads before the flag),
// relaxed atomic flag poll + compiler barrier. Flags run 0..1024 across both
// phases. seq slots are write-once -> plain cached loads OK; ring2 slots are
// re-used -> reads MUST be atomic (L1/L2-bypass, same mechanism as flags).
// Projections (W1*x(t), W2*h1(t)) are computed for step s+1 AFTER the flag-set
// of step s, i.e. inside the poll-wait window -> off the critical path.
__global__ __launch_bounds__(256, 1) void k_fused(
    const float* __restrict__ x,
    const ushort* __restrict__ W1pk, const ushort* __restrict__ U1pk,
    const float* __restrict__ bp1,
    const ushort* __restrict__ W2pk, const ushort* __restrict__ U2pk,
    const float* __restrict__ bp2,
    uint* __restrict__ seq, uint* __restrict__ ring2,
    int* __restrict__ flags) {
  int tid = threadIdx.x;
  int L = tid & 63;
  int ct = tid >> 6;            // wave id = col tile
  int jb = blockIdx.x >> 1;
  int bh = blockIdx.x & 1;
  int q = L >> 4, n = L & 15;
  int col = bh * 64 + ct * 16 + n;
  int j = jb * 4 + q;           // this lane's hidden unit
  int hrow = q * 8;             // B-frag k-offset within a 32-k tile
  int fi0 = bh * 128 + L;       // lane polls flags[fi0], flags[fi1]
  int fi1 = fi0 + 64;
  int fme = bh * 128 + jb;      // this block's flag

  // A-frags: U (16 kt) kept resident; W1 (4 kt) kept resident in phase A
  short8 uh[16], ul[16];
  short8 w1h[4], w1l[4];
  {
    const ushort* ub = U1pk + ((size_t)(jb * 16) * 64 + L) * 16;
#pragma unroll
    for (int kt = 0; kt < 16; ++kt) {
      uh[kt] = *(const short8*)(ub + kt * 1024);
      ul[kt] = *(const short8*)(ub + kt * 1024 + 8);
    }
    const ushort* wb = W1pk + ((size_t)(jb * 4) * 64 + L) * 16;
#pragma unroll
    for (int kt = 0; kt < 4; ++kt) {
      w1h[kt] = *(const short8*)(wb + kt * 1024);
      w1l[kt] = *(const short8*)(wb + kt * 1024 + 8);
    }
  }
  float4 bv = *(const float4*)(bp1 + j * 4);
  float c_reg = 0.f;            // c1_0 = 0; carried into phase B as c2_0 = c1_T
  const float* xb = x + (size_t)col * (TT * FF) + hrow;

  f32x4 a0 = {0.f, 0.f, 0.f, 0.f}, a1 = a0, a2 = a0;

  // W1 * x(S): B-frag built on the fly from fp32 x (hi/lo bf16 split, 3-term)
#define XPROJ(S) { \
    const float* xp = xb + (size_t)(S) * FF; \
    _Pragma("unroll") \
    for (int kt = 0; kt < 4; ++kt) { \
      float4 v0 = *(const float4*)(xp + kt * 32); \
      float4 v1 = *(const float4*)(xp + kt * 32 + 4); \
      float xf[8] = {v0.x, v0.y, v0.z, v0.w, v1.x, v1.y, v1.z, v1.w}; \
      short8 bhi, blo; \
      _Pragma("unroll") \
      for (int u = 0; u < 8; ++u) { \
        ushort hi = f2bf(xf[u]); \
        blo[u] = (short)f2bf(xf[u] - __uint_as_float(((uint)hi) << 16)); \
        bhi[u] = (short)hi; \
      } \
      a0 = MFMA(w1h[kt], bhi, a0, 0, 0, 0); \
      a1 = MFMA(w1l[kt], bhi, a1, 0, 0, 0); \
      a2 = MFMA(w1h[kt], blo, a2, 0, 0, 0); \
    } }

#define POLL(TGT) { \
    while (true) { \
      int f0 = __hip_atomic_load(&flags[fi0], __ATOMIC_RELAXED, __HIP_MEMORY_SCOPE_AGENT); \
      int f1 = __hip_atomic_load(&flags[fi1], __ATOMIC_RELAXED, __HIP_MEMORY_SCOPE_AGENT); \
      if (__all((f0 >= (TGT)) && (f1 >= (TGT)))) break; \
    } \
    asm volatile("" ::: "memory"); }

  // ---------------- phase A: layer 1, h-chain in seq ----------------
  XPROJ(0)
#pragma unroll 1
  for (int s = 0; s < TT; ++s) {
    if (s > 0) {
      POLL(s)
      // 16-deep prefetch of all 128 h words, then convert+MFMA
      const uint* hc = seq + (size_t)(s - 1) * HB + (size_t)hrow * BB + col;
      uint w[16][8];
#pragma unroll
      for (int kt = 0; kt < 16; ++kt)
#pragma unroll
        for (int u = 0; u < 8; ++u)
          w[kt][u] = hc[(size_t)(kt * 32 + u) * BB];
#pragma unroll
      for (int kt = 0; kt < 16; ++kt) {
        short8 bhi, blo;
#pragma unroll
        for (int u = 0; u < 8; ++u) {
          bhi[u] = (short)(w[kt][u] >> 16);
          blo[u] = (short)(w[kt][u] & 0xffffu);
        }
        a0 = MFMA(uh[kt], bhi, a0, 0, 0, 0);
        a1 = MFMA(ul[kt], bhi, a1, 0, 0, 0);
        a2 = MFMA(uh[kt], blo, a2, 0, 0, 0);
      }
    }
    float z0 = a0.x + a1.x + a2.x + bv.x;
    float z1 = a0.y + a1.y + a2.y + bv.y;
    float z2 = a0.z + a1.z + a2.z + bv.z;
    float z3 = a0.w + a1.w + a2.w + bv.w;
    float ig = 1.f / (1.f + __expf(-z0));
    float fg = 1.f / (1.f + __expf(-z1));
    float gg = tanhf(z2);
    float og = 1.f / (1.f + __expf(-z3));
    c_reg = fg * c_reg + ig * gg;
    float hn = og * tanhf(c_reg);
    ushort hi = f2bf(hn);
    uint word = (((uint)hi) << 16) |
                (uint)f2bf(hn - __uint_as_float(((uint)hi) << 16));
    __hip_atomic_store(&seq[(size_t)s * HB + (size_t)j * BB + col], word,
                       __ATOMIC_RELAXED, __HIP_MEMORY_SCOPE_AGENT);
    if (s == TT - 1)   // h2(-1) = h1(T-1) -> ring slot 3 (read atomically)
      __hip_atomic_store(&ring2[(size_t)3 * HB + (size_t)j * BB + col], word,
                         __ATOMIC_RELAXED, __HIP_MEMORY_SCOPE_AGENT);
    __syncthreads();   // drain all 4 waves' h stores before the flag
    if (tid == 0)
      __hip_atomic_store(&flags[fme], s + 1, __ATOMIC_RELAXED,
                         __HIP_MEMORY_SCOPE_AGENT);
    a0 = (f32x4){0.f, 0.f, 0.f, 0.f}; a1 = a0; a2 = a0;
    if (s + 1 < TT) XPROJ(s + 1)   // next step's x-proj in the wait window
  }

  // ---------------- phase B: layer 2, h-chain in ring2 ----------------
  {
    const ushort* ub = U2pk + ((size_t)(jb * 16) * 64 + L) * 16;
#pragma unroll
    for (int kt = 0; kt < 16; ++kt) {
      uh[kt] = *(const short8*)(ub + kt * 1024);
      ul[kt] = *(const short8*)(ub + kt * 1024 + 8);
    }
  }
  bv = *(const float4*)(bp2 + j * 4);
  const ushort* w2b = W2pk + ((size_t)(jb * 16) * 64 + L) * 16;

  // W2 * h1(S): seq is write-once and already flag-synced -> plain loads;
  // W2 frags streamed (32 KB/block, L1-resident after the first step)
#define G1PROJ(S) { \
    const uint* h1c = seq + (size_t)(S) * HB + (size_t)hrow * BB + col; \
    uint w[16][8]; \
    _Pragma("unroll") \
    for (int kt = 0; kt < 16; ++kt) \
      _Pragma("unroll") \
      for (int u = 0; u < 8; ++u) \
        w[kt][u] = h1c[(size_t)(kt * 32 + u) * BB]; \
    _Pragma("unroll") \
    for (int kt = 0; kt < 16; ++kt) { \
      short8 w2h = *(const short8*)(w2b + kt * 1024); \
      short8 w2l = *(const short8*)(w2b + kt * 1024 + 8); \
      short8 bhi, blo; \
      _Pragma("unroll") \
      for (int u = 0; u < 8; ++u) { \
        bhi[u] = (short)(w[kt][u] >> 16); \
        blo[u] = (short)(w[kt][u] & 0xffffu); \
      } \
      a0 = MFMA(w2h, bhi, a0, 0, 0, 0); \
      a1 = MFMA(w2l, bhi, a1, 0, 0, 0); \
      a2 = MFMA(w2h, blo, a2, 0, 0, 0); \
    } }

  G1PROJ(0)
#pragma unroll 1
  for (int s = 0; s < TT; ++s) {
    POLL(TT + s)   // s=0: all blocks finished phase A (seq + ring2[3] final)
    {
      const uint* hc = ring2 + (size_t)((s + 3) & 3) * HB + (size_t)hrow * BB + col;
      uint w[16][8];
#pragma unroll
      for (int kt = 0; kt < 16; ++kt)
#pragma unroll
        for (int u = 0; u < 8; ++u)
          w[kt][u] = __hip_atomic_load(&hc[(size_t)(kt * 32 + u) * BB],
                                       __ATOMIC_RELAXED, __HIP_MEMORY_SCOPE_AGENT);
#pragma unroll
      for (int kt = 0; kt < 16; ++kt) {
        short8 bhi, blo;
#pragma unroll
        for (int u = 0; u < 8; ++u) {
          bhi[u] = (short)(w[kt][u] >> 16);
          blo[u] = (short)(w[kt][u] & 0xffffu);
        }
        a0 = MFMA(uh[kt], bhi, a0, 0, 0, 0);
        a1 = MFMA(ul[kt], bhi, a1, 0, 0, 0);
        a2 = MFMA(uh[kt], blo, a2, 0, 0, 0);
      }
    }
    float z0 = a0.x + a1.x + a2.x + bv.x;
    float z1 = a0.y + a1.y + a2.y + bv.y;
    float z2 = a0.z + a1.z + a2.z + bv.z;
    float z3 = a0.w + a1.w + a2.w + bv.w;
    float ig = 1.f / (1.f + __expf(-z0));
    float fg = 1.f / (1.f + __expf(-z1));
    float gg = tanhf(z2);
    float og = 1.f / (1.f + __expf(-z3));
    c_reg = fg * c_reg + ig * gg;
    float hn = og * tanhf(c_reg);
    ushort hi = f2bf(hn);
    uint word = (((uint)hi) << 16) |
                (uint)f2bf(hn - __uint_as_float(((uint)hi) << 16));
    __hip_atomic_store(&ring2[(size_t)(s & 3) * HB + (size_t)j * BB + col], word,
                       __ATOMIC_RELAXED, __HIP_MEMORY_SCOPE_AGENT);
    __syncthreads();
    if (tid == 0)
      __hip_atomic_store(&flags[fme], TT + s + 1, __ATOMIC_RELAXED,
                         __HIP_MEMORY_SCOPE_AGENT);
    a0 = (f32x4){0.f, 0.f, 0.f, 0.f}; a1 = a0; a2 = a0;
    if (s + 1 < TT) G1PROJ(s + 1)  // next step's W2*h1 in the wait window
  }
}

// ---------------- dense + softmax ----------------
__global__ __launch_bounds__(64) void k_dense(const uint* __restrict__ h2,
                                              const float* __restrict__ Wd,
                                              const float* __restrict__ bd,
                                              float* __restrict__ out) {
  int b = blockIdx.x * 64 + threadIdx.x;
  float acc[10];
#pragma unroll
  for (int c = 0; c < 10; ++c) acc[c] = bd[c];
  for (int k = 0; k < HH; ++k) {
    uint w = h2[k * BB + b];
    float hv = __uint_as_float(w & 0xffff0000u) + __uint_as_float(w << 16);
#pragma unroll
    for (int c = 0; c < 10; ++c) acc[c] = fmaf(hv, Wd[k * 10 + c], acc[c]);
  }
  float m = acc[0];
#pragma unroll
  for (int c = 1; c < 10; ++c) m = fmaxf(m, acc[c]);
  float s = 0.f;
#pragma unroll
  for (int c = 0; c < 10; ++c) { acc[c] = __expf(acc[c] - m); s += acc[c]; }
  float inv = 1.f / s;
#pragma unroll
  for (int c = 0; c < 10; ++c) out[b * 10 + c] = acc[c] * inv;
}

// ---------------- host ----------------
extern "C" void kernel_launch(void* const* d_in, const int* in_sizes, int n_in,
                              void* d_out, int out_size, void* d_ws, size_t ws_size,
                              hipStream_t stream) {
  const float* x  = (const float*)d_in[0];
  const float* W1 = (const float*)d_in[1];
  const float* U1 = (const float*)d_in[2];
  const float* b1 = (const float*)d_in[3];
  const float* W2 = (const float*)d_in[4];
  const float* U2 = (const float*)d_in[5];
  const float* b2 = (const float*)d_in[6];
  const float* Wd = (const float*)d_in[7];
  const float* bd = (const float*)d_in[8];
  float* out = (float*)d_out;

  // layout (4-byte units); total ~37.2M units ~149 MB (< proven 181 MB)
  uint*   seq   = (uint*)d_ws;                      // [512][HB]      33,554,432
  uint*   ring2 = seq + (size_t)TT * HB;            // [4][HB]           262,144
  float*  bp1   = (float*)(ring2 + (size_t)4 * HB); //                     2,048
  float*  bp2   = bp1 + NR;                         //                     2,048
  ushort* W1pk  = (ushort*)(bp2 + NR);              //    524,288 ush
  ushort* U1pk  = W1pk + (size_t)524288;            //  2,097,152 ush
  ushort* U2pk  = U1pk + (size_t)2097152;           //  2,097,152 ush
  ushort* W2pk  = U2pk + (size_t)2097152;           //  2,097,152 ush
  int*    flags = (int*)(W2pk + (size_t)2097152);   //        256 ints

  k_zero<<<1, 256, 0, stream>>>((float*)flags, 256);
  k_rearr_b<<<NR / 256, 256, 0, stream>>>(b1, bp1);
  k_rearr_b<<<NR / 256, 256, 0, stream>>>(b2, bp2);
  k_pack_A<<<1024, 256, 0, stream>>>(W1, W1pk, 2);   // K=128 -> 4 k-tiles
  k_pack_A<<<4096, 256, 0, stream>>>(U1, U1pk, 4);   // K=512 -> 16 k-tiles
  k_pack_A<<<4096, 256, 0, stream>>>(U2, U2pk, 4);
  k_pack_A<<<4096, 256, 0, stream>>>(W2, W2pk, 4);

  k_fused<<<256, 256, 0, stream>>>(x, W1pk, U1pk, bp1, W2pk, U2pk, bp2,
                                   seq, ring2, flags);
  k_dense<<<BB / 64, 64, 0, stream>>>(ring2 + (size_t)3 * HB, Wd, bd, out);
}